// Round 10
// baseline (326.509 us; speedup 1.0000x reference)
//
#include <hip/hip_runtime.h>
#include <hip/hip_bf16.h>
#include <hip/hip_fp16.h>

typedef _Float16 half8 __attribute__((ext_vector_type(8)));
typedef _Float16 half4 __attribute__((ext_vector_type(4)));
typedef float    floatx4 __attribute__((ext_vector_type(4)));

#define BM  64
#define TPB 4   // tiles per persistent block

// ---------------------------------------------------------------------------
// Kernel 1: W in MFMA-fragment order. Element index:
//   idx = ((((l*4 + wc)*8 + s)*4 + nf)*64 + lane), value block = 8 halves (16 B)
//   content: W^T[n][k] * scale with n = wc*64+nf*16+(lane&15),
//            k = s*32 + (lane>>4)*8 + j
// A wave's B-fragment load is contiguous: base + lane*16.
// ---------------------------------------------------------------------------
__global__ void make_weights_frag(const float* __restrict__ p0, const float* __restrict__ p1,
                                  const float* __restrict__ p2, const float* __restrict__ p3,
                                  _Float16* __restrict__ wt) {
    int idx  = blockIdx.x * blockDim.x + threadIdx.x;   // 0 .. 24575
    int lane = idx & 63;
    int nf   = (idx >> 6) & 3;
    int s    = (idx >> 8) & 7;
    int wc   = (idx >> 11) & 3;
    int l    = idx >> 13;
    int n  = wc * 64 + nf * 16 + (lane & 15);
    int k0 = s * 32 + (lane >> 4) * 8;
    const float* P[4] = {p0, p1, p2, p3};
    const float* pb = P[l + 1] + n * 20;
    float pbr[20];
    #pragma unroll
    for (int i = 0; i < 20; ++i) pbr[i] = pb[i];
    half8 o;
    #pragma unroll
    for (int j = 0; j < 8; ++j) {
        const float* pa = P[l] + (k0 + j) * 20;
        float d2 = 0.f;
        #pragma unroll
        for (int i = 0; i < 20; ++i) { float df = pa[i] - pbr[i]; d2 += df * df; }
        float d = sqrtf(d2);
        float m = fmodf(d, 0.2f);                            // == np.mod, d >= 0
        o[j] = (_Float16)(10.0f * (0.05f - fabsf(m - 0.1f)) * 0.0625f);
    }
    *reinterpret_cast<half8*>(wt + (size_t)idx * 8) = o;
}

// ---------------------------------------------------------------------------
// Kernel 2: persistent fused 3-layer forward (R9 tile engine, static pipeline).
//   - 512 blocks x 512 threads; each block runs TPB=4 consecutive 64-row tiles
//     via a 2-tile statically-unrolled body (all LDS pointers compile-time).
//   - Wave wv owns all 64 rows x cols [wv*32,wv*32+32): acc[4][2]=32 regs,
//     W-dedup (block W traffic = 384 KB minimum).
//   - Per tile: l0 rd X wr Y; l1 rd Y wr X; l2 rd X, next x -> Y (two 16-reg
//     micro-batches inside l2's K-loop, >=3 K-steps latency cover each).
//   - out-stores issued AFTER the tile barrier -> drain under next tile's l0.
//   - W ring-prefetched 2 K-steps ahead (bb[3][2], static indices).
//   - 3 __syncthreads per tile.
// ---------------------------------------------------------------------------
__global__ __launch_bounds__(512, 4) void pcn_fused(
    const float* __restrict__ x, const _Float16* __restrict__ wt,
    const float* __restrict__ b1, const float* __restrict__ b2,
    const float* __restrict__ b3, float* __restrict__ out) {

    // z[row][k] in buf b: byte = b*32768 + row*512 + ((k/8)^(row&7))*16 + (k&7)*2
    __shared__ __align__(16) _Float16 zlds[2][BM * 256];   // 65,536 B

    const int t    = threadIdx.x;
    const int lane = t & 63;
    const int wv   = t >> 6;      // 0..7: column slice [wv*32, wv*32+32)
    const int l15  = lane & 15;
    const int lg   = lane >> 4;   // 0..3

    char* const zb0 = reinterpret_cast<char*>(&zlds[0][0]);
    char* const zb1 = reinterpret_cast<char*>(&zlds[1][0]);

    half8   bb[3][2];             // ring: step g uses bb[g%3]
    floatx4 acc[4][2];
    floatx4 xr[4];                // x staging micro-batch (16 regs)

    // W fragment address for global step g (= l*8+s), col sub-frag j (0..1)
    auto wfrag = [&](int g, int j) -> const half8* {
        const int gl = g >> 3, gs = g & 7;
        return reinterpret_cast<const half8*>(
            wt + (((size_t)gl * 4 + (wv >> 1)) << 14) + gs * 2048
               + ((wv & 1) * 2 + j) * 512 + lane * 8);
    };

    // x micro-batch b (0: rows 0-31, 1: rows 32-63) of the 64x256 f32 tile
    auto xload_batch = [&](size_t r0, int b) {
        #pragma unroll
        for (int i = 0; i < 4; ++i) {
            int g   = (b * 4 + i) * 512 + t;     // float4 index in [64][64]
            int row = g >> 6, c4 = g & 63;
            xr[i] = *reinterpret_cast<const floatx4*>(x + (r0 + row) * 256 + c4 * 4);
        }
    };
    auto xwrite_batch = [&](char* zb, int b) {
        #pragma unroll
        for (int i = 0; i < 4; ++i) {
            int g   = (b * 4 + i) * 512 + t;
            int row = g >> 6, c4 = g & 63;
            half4 h;
            h[0] = (_Float16)xr[i][0]; h[1] = (_Float16)xr[i][1];
            h[2] = (_Float16)xr[i][2]; h[3] = (_Float16)xr[i][3];
            int chunk = (c4 >> 1) ^ (row & 7);
            *reinterpret_cast<half4*>(zb + row * 512 + chunk * 16 + (c4 & 1) * 8) = h;
        }
    };

    const size_t tile0 = (size_t)blockIdx.x * (TPB * BM);

    // ---- prologue: stage tile 0 -> zb0; prefetch W g=0,1; sync
    xload_batch(tile0, 0); xwrite_batch(zb0, 0);
    xload_batch(tile0, 1); xwrite_batch(zb0, 1);
    #pragma unroll
    for (int j = 0; j < 2; ++j) bb[0][j] = *wfrag(0, j);
    #pragma unroll
    for (int j = 0; j < 2; ++j) bb[1][j] = *wfrag(1, j);
    __syncthreads();

    // one tile: x/z2 live in bufX, scratch z1/next-x in bufY
    auto do_tile = [&](size_t row0, char* bufX, char* bufY, bool pfx, bool last) {
        #pragma unroll
        for (int l = 0; l < 3; ++l) {
            const float* bias = (l == 0) ? b1 : (l == 1) ? b2 : b3;
            char* const rz = (l == 1) ? bufY : bufX;

            #pragma unroll
            for (int j = 0; j < 2; ++j) {
                const float bv = bias[wv * 32 + j * 16 + l15];
                #pragma unroll
                for (int mf = 0; mf < 4; ++mf)
                    acc[mf][j] = floatx4{bv, bv, bv, bv};
            }

            #pragma unroll
            for (int s = 0; s < 8; ++s) {        // K-step of 32; global step g
                const int g = l * 8 + s;
                if (g + 2 < 24) {
                    #pragma unroll
                    for (int j = 0; j < 2; ++j)
                        bb[(g + 2) % 3][j] = *wfrag(g + 2, j);
                }
                // stream next tile's x into bufY (free since l1-epi barrier):
                // load s0 -> write s3 (3 steps cover), load s4 -> write post-loop
                if (l == 2 && pfx) {
                    if (s == 0) xload_batch(row0 + BM, 0);
                    if (s == 3) xwrite_batch(bufY, 0);
                    if (s == 4) xload_batch(row0 + BM, 1);
                }
                const int vchunk = (s * 4 + lg) ^ (l15 & 7);
                half8 a[4];
                #pragma unroll
                for (int mf = 0; mf < 4; ++mf)
                    a[mf] = *reinterpret_cast<const half8*>(
                        rz + (mf * 16 + l15) * 512 + vchunk * 16);
                #pragma unroll
                for (int mf = 0; mf < 4; ++mf)
                    #pragma unroll
                    for (int j = 0; j < 2; ++j)
                        acc[mf][j] = __builtin_amdgcn_mfma_f32_16x16x32_f16(
                            a[mf], bb[g % 3][j], acc[mf][j], 0, 0, 0);
            }

            if (l < 2) {
                // relu + cvt -> the buffer NOT being read this phase
                char* const wz = (l == 0) ? bufY : bufX;
                #pragma unroll
                for (int j = 0; j < 2; ++j) {
                    const int n = wv * 32 + j * 16 + l15;
                    #pragma unroll
                    for (int mf = 0; mf < 4; ++mf) {
                        const int mrow = mf * 16 + lg * 4;
                        #pragma unroll
                        for (int r = 0; r < 4; ++r) {
                            float v = fmaxf(acc[mf][j][r], 0.0f);
                            const int row  = mrow + r;
                            const int byte = row * 512 + (((n >> 3) ^ (row & 7)) << 4)
                                           + (n & 7) * 2;
                            *reinterpret_cast<_Float16*>(wz + byte) = (_Float16)v;
                        }
                    }
                }
                __syncthreads();
            }
        }

        // finish next-x staging + refill W ring for the next tile
        if (pfx) {
            xwrite_batch(bufY, 1);               // 4 steps of latency cover
            #pragma unroll
            for (int j = 0; j < 2; ++j) bb[0][j] = *wfrag(0, j);
            #pragma unroll
            for (int j = 0; j < 2; ++j) bb[1][j] = *wfrag(1, j);
        }
        if (!last) __syncthreads();

        // out-stores AFTER the barrier: drain in background under next l0
        #pragma unroll
        for (int j = 0; j < 2; ++j) {
            const int n = wv * 32 + j * 16 + l15;
            #pragma unroll
            for (int mf = 0; mf < 4; ++mf) {
                const size_t mrow = row0 + mf * 16 + lg * 4;
                #pragma unroll
                for (int r = 0; r < 4; ++r)
                    out[(mrow + r) * 256 + n] = acc[mf][j][r];
            }
        }
    };

    #pragma unroll 1
    for (int it2 = 0; it2 < TPB / 2; ++it2) {
        const size_t rowA = tile0 + (size_t)it2 * (2 * BM);
        do_tile(rowA,      zb0, zb1, true,      false);
        do_tile(rowA + BM, zb1, zb0, it2 == 0,  it2 == 1);
    }
}

extern "C" void kernel_launch(void* const* d_in, const int* in_sizes, int n_in,
                              void* d_out, int out_size, void* d_ws, size_t ws_size,
                              hipStream_t stream) {
    const float* x  = (const float*)d_in[0];
    const float* p0 = (const float*)d_in[1];
    const float* p1 = (const float*)d_in[2];
    const float* p2 = (const float*)d_in[3];
    const float* p3 = (const float*)d_in[4];
    const float* b1 = (const float*)d_in[5];
    const float* b2 = (const float*)d_in[6];
    const float* b3 = (const float*)d_in[7];
    float* out = (float*)d_out;
    _Float16* wt = (_Float16*)d_ws;              // 3*4*8*4*64*8 halves = 384 KB

    const int B = in_sizes[0] / 256;             // 131072

    make_weights_frag<<<96, 256, 0, stream>>>(p0, p1, p2, p3, wt);
    pcn_fused<<<B / (BM * TPB), 512, 0, stream>>>(x, wt, b1, b2, b3, out);
}

// Round 11
// 86.845 us; speedup vs baseline: 3.7597x; 3.7597x over previous
//
#include <hip/hip_runtime.h>
#include <hip/hip_bf16.h>
#include <hip/hip_fp16.h>

typedef _Float16 half8 __attribute__((ext_vector_type(8)));
typedef _Float16 half4 __attribute__((ext_vector_type(4)));
typedef float    floatx4 __attribute__((ext_vector_type(4)));

#define BM 64

// ---------------------------------------------------------------------------
// Kernel 1: W in MFMA-fragment order. Element index:
//   idx = ((((l*4 + wc)*8 + s)*4 + nf)*64 + lane), value block = 8 halves (16 B)
//   content: W^T[n][k] * scale with n = wc*64+nf*16+(lane&15),
//            k = s*32 + (lane>>4)*8 + j
// A wave's W-fragment load is contiguous: base + lane*16.
// ---------------------------------------------------------------------------
__global__ void make_weights_frag(const float* __restrict__ p0, const float* __restrict__ p1,
                                  const float* __restrict__ p2, const float* __restrict__ p3,
                                  _Float16* __restrict__ wt) {
    int idx  = blockIdx.x * blockDim.x + threadIdx.x;   // 0 .. 24575
    int lane = idx & 63;
    int nf   = (idx >> 6) & 3;
    int s    = (idx >> 8) & 7;
    int wc   = (idx >> 11) & 3;
    int l    = idx >> 13;
    int n  = wc * 64 + nf * 16 + (lane & 15);
    int k0 = s * 32 + (lane >> 4) * 8;
    const float* P[4] = {p0, p1, p2, p3};
    const float* pb = P[l + 1] + n * 20;
    float pbr[20];
    #pragma unroll
    for (int i = 0; i < 20; ++i) pbr[i] = pb[i];
    half8 o;
    #pragma unroll
    for (int j = 0; j < 8; ++j) {
        const float* pa = P[l] + (k0 + j) * 20;
        float d2 = 0.f;
        #pragma unroll
        for (int i = 0; i < 20; ++i) { float df = pa[i] - pbr[i]; d2 += df * df; }
        float d = sqrtf(d2);
        float m = fmodf(d, 0.2f);                            // == np.mod, d >= 0
        o[j] = (_Float16)(10.0f * (0.05f - fabsf(m - 0.1f)) * 0.0625f);
    }
    *reinterpret_cast<half8*>(wt + (size_t)idx * 8) = o;
}

// ---------------------------------------------------------------------------
// Kernel 2: fused 3-layer forward — R9 shell + SWAPPED MFMA OPERANDS.
//   mfma(W_frag, z_frag, acc): D col(l15) = z-row m, D reg-axis (lg*4+r) =
//   output col n -> each lane holds 4 CONSECUTIVE n per fragment:
//     * inner epilogues: 8 x ds_write_b64 (half4) instead of 32 x b16
//     * out-store: 8 x global_store_dwordx4 instead of 32 x dword
//     * bias init: float4 load instead of scalar broadcast
//   K-loop identical to R9 (same ds_reads, same W ring prefetch, same MFMAs).
//   - 512 threads, 8 waves; wave wv owns all 64 rows x cols [wv*32,wv*32+32)
//     (W-dedup: block W traffic = 384 KB minimum). acc[2][4] = 32 regs.
//   - z ping-pong: two 32 KB XOR-swizzled LDS buffers, compile-time pointers;
//     l0 rd b0 wr b1, l1 rd b1 wr b0, l2 rd b0 -> out. 3 barriers/block.
//   - W ring-prefetched 2 K-steps ahead (bb[3][2], static indices).
// ---------------------------------------------------------------------------
__global__ __launch_bounds__(512, 4) void pcn_fused(
    const float* __restrict__ x, const _Float16* __restrict__ wt,
    const float* __restrict__ b1, const float* __restrict__ b2,
    const float* __restrict__ b3, float* __restrict__ out) {

    // z[row][k] in buf b: byte = b*32768 + row*512 + ((k/8)^(row&7))*16 + (k&7)*2
    __shared__ __align__(16) _Float16 zlds[2][BM * 256];   // 65,536 B

    const int t    = threadIdx.x;
    const int lane = t & 63;
    const int wv   = t >> 6;      // 0..7: column slice [wv*32, wv*32+32)
    const int l15  = lane & 15;
    const int lg   = lane >> 4;   // 0..3
    const size_t row0 = (size_t)blockIdx.x * BM;

    char* const zb0 = reinterpret_cast<char*>(&zlds[0][0]);
    char* const zb1 = reinterpret_cast<char*>(&zlds[1][0]);

    half8   bb[3][2];             // ring: step g uses bb[g%3]
    floatx4 acc[2][4];            // [j: n-16-block][mf: m-16-block]

    // W fragment address for global step g (= l*8+s), col sub-frag j (0..1)
    auto wfrag = [&](int g, int j) -> const half8* {
        const int gl = g >> 3, gs = g & 7;
        return reinterpret_cast<const half8*>(
            wt + (((size_t)gl * 4 + (wv >> 1)) << 14) + gs * 2048
               + ((wv & 1) * 2 + j) * 512 + lane * 8);
    };

    // ---- stage x: 64x256 f32 -> fp16 swizzled into buf0. 8 float4/thread.
    {
        floatx4 xr[8];
        #pragma unroll
        for (int i = 0; i < 8; ++i) {
            int g   = i * 512 + t;        // float4 index in [64][64]
            int row = g >> 6, c4 = g & 63;
            xr[i] = *reinterpret_cast<const floatx4*>(x + (row0 + row) * 256 + c4 * 4);
        }
        #pragma unroll
        for (int i = 0; i < 8; ++i) {
            int g   = i * 512 + t;
            int row = g >> 6, c4 = g & 63;
            half4 h;
            h[0] = (_Float16)xr[i][0]; h[1] = (_Float16)xr[i][1];
            h[2] = (_Float16)xr[i][2]; h[3] = (_Float16)xr[i][3];
            int chunk = (c4 >> 1) ^ (row & 7);
            *reinterpret_cast<half4*>(zb0 + row * 512 + chunk * 16 + (c4 & 1) * 8) = h;
        }
    }
    // prefetch W steps g=0,1 while x-writes drain
    #pragma unroll
    for (int j = 0; j < 2; ++j) bb[0][j] = *wfrag(0, j);
    #pragma unroll
    for (int j = 0; j < 2; ++j) bb[1][j] = *wfrag(1, j);
    __syncthreads();

    #pragma unroll
    for (int l = 0; l < 3; ++l) {
        const float* bias = (l == 0) ? b1 : (l == 1) ? b2 : b3;
        char* const rz = (l == 1) ? zb1 : zb0;     // layer input buffer

        // bias -> accumulator init: lane holds n = wv*32 + j*16 + lg*4 + r
        #pragma unroll
        for (int j = 0; j < 2; ++j) {
            const floatx4 bv4 = *reinterpret_cast<const floatx4*>(
                bias + wv * 32 + j * 16 + lg * 4);
            #pragma unroll
            for (int mf = 0; mf < 4; ++mf)
                acc[j][mf] = bv4;
        }

        #pragma unroll
        for (int s = 0; s < 8; ++s) {            // K-step of 32; global step g
            const int g = l * 8 + s;
            if (g + 2 < 24) {
                #pragma unroll
                for (int j = 0; j < 2; ++j)
                    bb[(g + 2) % 3][j] = *wfrag(g + 2, j);
            }
            const int vchunk = (s * 4 + lg) ^ (l15 & 7);
            half8 a[4];
            #pragma unroll
            for (int mf = 0; mf < 4; ++mf)
                a[mf] = *reinterpret_cast<const half8*>(
                    rz + (mf * 16 + l15) * 512 + vchunk * 16);
            // SWAPPED operands: first = W frag (n-axis), second = z frag (m-axis)
            #pragma unroll
            for (int j = 0; j < 2; ++j)
                #pragma unroll
                for (int mf = 0; mf < 4; ++mf)
                    acc[j][mf] = __builtin_amdgcn_mfma_f32_16x16x32_f16(
                        bb[g % 3][j], a[mf], acc[j][mf], 0, 0, 0);
        }

        if (l < 2) {
            // relu + cvt -> the OTHER buffer. Lane holds z[m][k0..k0+3]:
            // m = mf*16 + l15, k0 = wv*32 + j*16 + lg*4 -> one half4 per frag.
            char* const wz = (l == 0) ? zb1 : zb0;
            #pragma unroll
            for (int j = 0; j < 2; ++j) {
                const int k0 = wv * 32 + j * 16 + lg * 4;
                #pragma unroll
                for (int mf = 0; mf < 4; ++mf) {
                    const int m = mf * 16 + l15;
                    half4 h;
                    #pragma unroll
                    for (int r = 0; r < 4; ++r)
                        h[r] = (_Float16)fmaxf(acc[j][mf][r], 0.0f);
                    const int byte = m * 512 + (((k0 >> 3) ^ (m & 7)) << 4)
                                   + (k0 & 7) * 2;
                    *reinterpret_cast<half4*>(wz + byte) = h;
                }
            }
            __syncthreads();
        } else {
            // final layer: float4 stores. Lane holds out[m][n0..n0+3].
            #pragma unroll
            for (int j = 0; j < 2; ++j) {
                const int n0 = wv * 32 + j * 16 + lg * 4;
                #pragma unroll
                for (int mf = 0; mf < 4; ++mf) {
                    const size_t m = row0 + mf * 16 + l15;
                    *reinterpret_cast<floatx4*>(out + m * 256 + n0) = acc[j][mf];
                }
            }
        }
    }
}

extern "C" void kernel_launch(void* const* d_in, const int* in_sizes, int n_in,
                              void* d_out, int out_size, void* d_ws, size_t ws_size,
                              hipStream_t stream) {
    const float* x  = (const float*)d_in[0];
    const float* p0 = (const float*)d_in[1];
    const float* p1 = (const float*)d_in[2];
    const float* p2 = (const float*)d_in[3];
    const float* p3 = (const float*)d_in[4];
    const float* b1 = (const float*)d_in[5];
    const float* b2 = (const float*)d_in[6];
    const float* b3 = (const float*)d_in[7];
    float* out = (float*)d_out;
    _Float16* wt = (_Float16*)d_ws;              // 3*4*8*4*64*8 halves = 384 KB

    const int B = in_sizes[0] / 256;             // 131072

    make_weights_frag<<<96, 256, 0, stream>>>(p0, p1, p2, p3, wt);
    pcn_fused<<<B / BM, 512, 0, stream>>>(x, wt, b1, b2, b3, out);
}